// Round 1
// baseline (128.459 us; speedup 1.0000x reference)
//
#include <hip/hip_runtime.h>

// Problem dims
#define NZ 128
#define NY 192
#define NXP 193
#define NX 192
#define NVOX (NZ * NY * NX)
#define NZ0 (NZ * NY)      // 24576

// Tile: 32 x 16 xy outputs per block, 8 z-outputs per thread.
// Two y-chains (y, y+8) packed into the two f16 lanes of a native _Float16x2
// (R10: WIN, 104.5 -> 95.7). R11: the z-loop is NOT unrolled (single 2-step
// body + register rotation) to shrink I-footprint ~4x.
// R12 (this round): single-kernel fusion. ~84 us of the measured time is the
// harness's two 256-MiB workspace poisons (fills at ~6.4 TB/s = HBM roofline);
// our controllable portion is ~12 us. The old final_k serialized ~5-6 us
// (launch + single-block median select) AFTER the tiles, but its expensive
// part depends only on the 96 gather blocks. Now: a dedicated selector block
// overlaps the median select with tile compute; the last tile block reduces
// the partials and writes out. Device-scope fences per XCD-coherence rules.
#define TX 32
#define TY 16
#define TZ 8
#define LX 34              // TX + 2
#define LYP 10             // packed rows r=0..9 (low: d rows -1..8, high: 7..16)
#define LZ 10              // TZ + 2
#define LSLP (LYP * LX)    // 340 packed entries per z-slice
#define LTOTP (LZ * LSLP)  // 3400 half2 = 13600 B

#define GX (NX / TX)       // 6
#define GY (NY / TY)       // 12
#define GZ (NZ / TZ)       // 16
#define NBLK (GX * GY * GZ) // 1152
#define ZB (NZ0 / 256)     // 96 z0-gather blocks (dispatched first)
#define NGRID (ZB + 1 + NBLK) // gathers + selector + tiles

// Device-global scratch. Lifecycle: every counter/flag returns to 0 before
// the dispatch ends (reset by its last consumer), g_hist re-zeroed by the
// selector, g_ps/g_pm/g_u/g_med fully overwritten every call before read.
__device__ double   g_ps[NBLK];
__device__ float    g_pm[NBLK];
__device__ unsigned g_hist[2048];
__device__ unsigned g_u[NZ0];
__device__ unsigned g_cnt_g;   // gather blocks done
__device__ unsigned g_cnt_t;   // tile blocks done
__device__ unsigned g_flag;    // median published
__device__ unsigned g_med;     // sortable-encoded median

__device__ __forceinline__ int refl(int i, int n) {
    i = (i < 0) ? -i : i;
    i = (i >= n) ? (2 * n - 2 - i) : i;
    return i;
}

__device__ __forceinline__ unsigned f2sortable(float f) {
    unsigned bits = __float_as_uint(f);
    return bits ^ ((bits & 0x80000000u) ? 0xFFFFFFFFu : 0x80000000u);
}

// Native packed f16 pair: clang ext vector, no hip_fp16.h API dependence.
typedef _Float16 H2 __attribute__((ext_vector_type(2)));

static __device__ __forceinline__ H2 h2min(H2 a, H2 b) { return __builtin_elementwise_min(a, b); }
static __device__ __forceinline__ H2 h2max(H2 a, H2 b) { return __builtin_elementwise_max(a, b); }

// ---- Batcher odd-even merge / sort on packed pairs (topology verified
// rounds 2-10; unused merge outputs are DCE'd by the compiler) ----
template<int M, int N>
struct OEM {
    static __device__ __forceinline__ void run(const H2* a, const H2* b, H2* out) {
        if constexpr (M == 0) {
#pragma unroll
            for (int i = 0; i < N; ++i) out[i] = b[i];
        } else if constexpr (N == 0) {
#pragma unroll
            for (int i = 0; i < M; ++i) out[i] = a[i];
        } else if constexpr (M == 1 && N == 1) {
            out[0] = h2min(a[0], b[0]);
            out[1] = h2max(a[0], b[0]);
        } else {
            constexpr int ME = (M + 1) / 2, MO = M / 2, NE = (N + 1) / 2, NO = N / 2;
            H2 ae[ME], be[NE];
            H2 ao[MO > 0 ? MO : 1], bo[NO > 0 ? NO : 1];
#pragma unroll
            for (int i = 0; i < ME; ++i) ae[i] = a[2 * i];
#pragma unroll
            for (int i = 0; i < MO; ++i) ao[i] = a[2 * i + 1];
#pragma unroll
            for (int i = 0; i < NE; ++i) be[i] = b[2 * i];
#pragma unroll
            for (int i = 0; i < NO; ++i) bo[i] = b[2 * i + 1];
            constexpr int EL = ME + NE, OL = MO + NO;
            H2 e[EL];
            H2 o[OL > 0 ? OL : 1];
            OEM<ME, NE>::run(ae, be, e);
            OEM<MO, NO>::run(ao, bo, o);
            constexpr int P = (OL < EL - 1) ? OL : (EL - 1);
            out[0] = e[0];
#pragma unroll
            for (int i = 0; i < P; ++i) {
                out[2 * i + 1] = h2min(o[i], e[i + 1]);
                out[2 * i + 2] = h2max(o[i], e[i + 1]);
            }
            if constexpr (EL == OL)           out[M + N - 1] = o[OL - 1];
            else if constexpr (EL == OL + 2)  out[M + N - 1] = e[EL - 1];
        }
    }
};

template<int N>
struct OES {
    static __device__ __forceinline__ void run(const H2* in, H2* out) {
        if constexpr (N == 1) {
            out[0] = in[0];
        } else {
            constexpr int H = N / 2;
            H2 s1[H], s2[N - H];
            OES<H>::run(in, s1);
            OES<N - H>::run(in + H, s2);
            OEM<H, N - H>::run(s1, s2, out);
        }
    }
};

// med27 = min( M[13], min_i max(A[i], M[12-i]) ), packed over both chains
__device__ __forceinline__ H2 sel27(const H2* A, const H2* M) {
    H2 t0 = h2max(A[0], M[12]);
    H2 t1 = h2max(A[1], M[11]);
    H2 t2 = h2max(A[2], M[10]);
    H2 t3 = h2max(A[3], M[9]);
    H2 t4 = h2max(A[4], M[8]);
    H2 t5 = h2max(A[5], M[7]);
    H2 t6 = h2max(A[6], M[6]);
    H2 t7 = h2max(A[7], M[5]);
    H2 t8 = h2max(A[8], M[4]);
    H2 r0 = h2min(h2min(t0, t1), h2min(t2, t3));
    H2 r1 = h2min(h2min(t4, t5), h2min(t6, t7));
    return h2min(h2min(r0, r1), h2min(t8, M[13]));
}

// Rank-locate across NB = PER*256 buckets with 256 threads (4 waves).
// Writes *s_b = bucket index containing rank kk, *s_r = rank within bucket.
// Ends with __syncthreads() so callers may read s_b/s_r immediately.
template<int PER>
__device__ __forceinline__ void pick256(const unsigned* __restrict__ h, unsigned kk,
                                        unsigned* s_b, unsigned* s_r,
                                        unsigned* wsum, unsigned* woff) {
    const int tid = threadIdx.x;
    const int lane = tid & 63, wid = tid >> 6;
    unsigned v[PER];
    unsigned mysum = 0u;
#pragma unroll
    for (int j = 0; j < PER; ++j) { v[j] = h[tid * PER + j]; mysum += v[j]; }
    unsigned inc = mysum;
#pragma unroll
    for (int d = 1; d < 64; d <<= 1) { unsigned t = __shfl_up(inc, d); if (lane >= d) inc += t; }
    if (lane == 63) wsum[wid] = inc;
    __syncthreads();
    if (tid == 0) { unsigned a = 0; for (int w = 0; w < 4; ++w) { woff[w] = a; a += wsum[w]; } }
    __syncthreads();
    unsigned exc = woff[wid] + inc - mysum;
#pragma unroll
    for (int j = 0; j < PER; ++j) {
        if (exc <= kk && kk < exc + v[j]) { *s_b = (unsigned)(tid * PER + j); *s_r = kk - exc; }
        exc += v[j];
    }
    __syncthreads();
}

// Fused single kernel:
//   blocks 0..ZB-1      : z0 gather + global histogram, signal g_cnt_g
//   block  ZB           : selector — waits for gathers, computes the global
//                         median (overlapped with tile compute), publishes it
//   blocks ZB+1..ZB+NBLK: loss tiles; the LAST one to finish reduces the
//                         per-block partials and writes out[0..2]
__global__ __launch_bounds__(256, 4) void fused_main(const float* __restrict__ P,
                                                     float* __restrict__ out) {
    __shared__ H2 dt[LTOTP];
    const int tid = threadIdx.x;
    const int bid = blockIdx.x;

    if (bid < ZB) {
        // ---- z0 gather + histogram role (exact f32 path, untouched) ----
        unsigned* h = (unsigned*)dt;
        for (int j = tid; j < 2048; j += 256) h[j] = 0u;
        __syncthreads();
        const int i = bid * 256 + tid;
        unsigned u = f2sortable(P[(size_t)i * NXP]);
        g_u[i] = u;
        atomicAdd(&h[u >> 21], 1u);
        __syncthreads();
        for (int j = tid; j < 2048; j += 256) {
            unsigned c = h[j];
            if (c) atomicAdd(&g_hist[j], c);
        }
        // release: make g_u plain stores + hist atomics visible device-wide
        __threadfence();
        __syncthreads();
        if (tid == 0) atomicAdd(&g_cnt_g, 1u);
        return;
    }

    if (bid == ZB) {
        // ---- selector role: median select overlapped with tile compute ----
        __shared__ unsigned wsum[4], woff[4];
        __shared__ unsigned s_b, s_r, s_cnt, s_med;
        unsigned* cand = (unsigned*)dt;   // reuse tile LDS (13600 B >= 8192)
        const unsigned kk = (NZ0 - 1) / 2;   // 12287

        if (tid == 0) {
            while (atomicAdd(&g_cnt_g, 0u) < ZB) __builtin_amdgcn_s_sleep(2);
        }
        __syncthreads();
        __threadfence();   // acquire: invalidate stale lines before g_u/g_hist reads

        // 1. pick the top-11-bit bucket containing rank kk
        pick256<8>(g_hist, kk, &s_b, &s_r, wsum, woff);
        const unsigned b1 = s_b, k1 = s_r;
        // re-zero g_hist for the next call (values already consumed)
        for (int j = tid; j < 2048; j += 256) g_hist[j] = 0u;

        // 2. gather in-bucket candidates, exact counting-select
        if (tid == 0) s_cnt = 0u;
        __syncthreads();
        for (int i = tid; i < NZ0; i += 256) {
            unsigned u = g_u[i];
            if ((u >> 21) == b1) {
                unsigned idx = atomicAdd(&s_cnt, 1u);
                if (idx < 2048u) cand[idx] = u;
            }
        }
        __syncthreads();
        const unsigned m = s_cnt;

        if (m <= 2048u) {
            for (int i = tid; i < (int)m; i += 256) {
                unsigned c = cand[i], less = 0u, eq = 0u;
                for (unsigned j = 0; j < m; ++j) {
                    unsigned v = cand[j];
                    less += (v < c); eq += (v == c);
                }
                if (less <= k1 && k1 < less + eq) s_med = c;
            }
            __syncthreads();
        } else {
            // fallback: 11-bit + 10-bit radix passes over g_u (filtered)
            unsigned pref = b1, kx = k1;
            for (int j = tid; j < 2048; j += 256) cand[j] = 0u;
            __syncthreads();
            for (int i = tid; i < NZ0; i += 256) {
                unsigned u = g_u[i];
                if ((u >> 21) == pref) atomicAdd(&cand[(u >> 10) & 2047u], 1u);
            }
            __syncthreads();
            pick256<8>(cand, kx, &s_b, &s_r, wsum, woff);
            pref = (pref << 11) | s_b; kx = s_r;
            __syncthreads();
            for (int j = tid; j < 1024; j += 256) cand[j] = 0u;
            __syncthreads();
            for (int i = tid; i < NZ0; i += 256) {
                unsigned u = g_u[i];
                if ((u >> 10) == pref) atomicAdd(&cand[u & 1023u], 1u);
            }
            __syncthreads();
            pick256<4>(cand, kx, &s_b, &s_r, wsum, woff);
            if (tid == 0) s_med = (pref << 10) | s_b;
            __syncthreads();
        }

        // publish median; reset gather counter for the next call
        if (tid == 0) {
            g_med = s_med;
            atomicExch(&g_cnt_g, 0u);
            __threadfence();              // release g_med before the flag
            atomicExch(&g_flag, 1u);
        }
        return;
    }

    // ---- loss tile role ----
    const int bf = bid - ZB - 1;
    const int bx = bf % GX;
    const int brem = bf / GX;
    const int by = brem % GY;
    const int bz = brem / GY;
    const int x0 = bx * TX, y0 = by * TY, z0t = bz * TZ;

    // Stage packed d-tile into LDS. Entry p: xx = p%LX, rr = p/LX; low half
    // from d row y0+rr-1, high half from d row y0+rr+7 (both reflect-mapped).
    int offL[2], offH[2], lp[2];
#pragma unroll
    for (int k = 0; k < 2; ++k) {
        int p = tid + 256 * k;
        lp[k] = (p < LSLP) ? p : -1;
        if (p < LSLP) {
            int xx = p % LX, rr = p / LX;
            int gx  = refl(x0 + xx - 1, NX);
            int gyL = refl(y0 + rr - 1, NY);
            int gyH = refl(y0 + rr + 7, NY);
            offL[k] = gyL * NXP + gx;
            offH[k] = gyH * NXP + gx;
        }
    }
    for (int zz = 0; zz < LZ; ++zz) {
        int gz = refl(z0t + zz - 1, NZ);
        const float* __restrict__ pl = P + (size_t)gz * (NY * NXP);
#pragma unroll
        for (int k = 0; k < 2; ++k) {
            if (lp[k] >= 0) {
                float dL = pl[offL[k] + 1] - pl[offL[k]];
                float dH = pl[offH[k] + 1] - pl[offH[k]];
                H2 v;
                v.x = (_Float16)dL;
                v.y = (_Float16)dH;
                dt[zz * LSLP + lp[k]] = v;
            }
        }
    }
    __syncthreads();

    const int x = tid & 31;
    const int y = tid >> 5;            // 0..7; packed rows y..y+2 serve y and y+8
    const int rbase = y * LX + x;

    auto rd9 = [&](int base, H2* v) {
#pragma unroll
        for (int dy = 0; dy < 3; ++dy)
#pragma unroll
            for (int dxx = 0; dxx < 3; ++dxx)
                v[dy * 3 + dxx] = dt[base + dy * LX + dxx];
    };

    H2 S0[9], S1[9], S2[9], T[9], M[18];
    H2 c2, m2 = (H2)((_Float16)0.0f);
    const H2 one2 = (H2)((_Float16)1.0f);
    float s_acc = 0.0f;

    // Warm-up: sorted slices 0 (S0) and 1 (S1); center of slice 1.
    rd9(rbase, T);            OES<9>::run(T, S0);
    rd9(rbase + LSLP, T);     c2 = T[4];
    OES<9>::run(T, S1);

    auto accum = [&](H2 med) {
        H2 df = c2 - med;
        float dl = (float)df.x, dh = (float)df.y;
        s_acc = fmaf(dl, dl, fmaf(dh, dh, s_acc));
        m2 = h2max(m2, one2 - c2);
    };

    // Invariant at pair t: S0 = sorted slice t (oldest), S1 = sorted t+1.
    // NOT unrolled: single ~2KB body keeps the I-footprint small (R11).
    int sl = rbase + 2 * LSLP;
#pragma unroll 1
    for (int t = 0; t < TZ; t += 2) {
        rd9(sl, T);
        H2 cn = T[4];
        OES<9>::run(T, S2);
        OEM<9, 9>::run(S1, S2, M);
        accum(sel27(S0, M));
        c2 = cn;
        sl += LSLP;

        rd9(sl, T);
        cn = T[4];
        OES<9>::run(T, S0);
        accum(sel27(S0, M));
        c2 = cn;
        sl += LSLP;

        // Rotate for next pair: S0' = sorted(t+2) = S2, S1' = sorted(t+3) = S0.
#pragma unroll
        for (int i = 0; i < 9; ++i) {
            H2 tmp = S0[i];
            S0[i] = S2[i];
            S1[i] = tmp;
        }
    }

    float m_acc = fmaxf((float)m2.x, (float)m2.y);

    // Block reduction -> per-block partial (plain stores, no atomics).
#pragma unroll
    for (int off = 32; off > 0; off >>= 1) {
        s_acc += __shfl_down(s_acc, off);
        m_acc = fmaxf(m_acc, __shfl_down(m_acc, off));
    }
    __shared__ float ss[4], sm[4];
    __shared__ int s_fin;
    const int lane = tid & 63, wid = tid >> 6;
    if (lane == 0) { ss[wid] = s_acc; sm[wid] = m_acc; }
    __syncthreads();
    if (tid == 0) {
        float S = (ss[0] + ss[1]) + (ss[2] + ss[3]);
        float M2 = fmaxf(fmaxf(sm[0], sm[1]), fmaxf(sm[2], sm[3]));
        g_ps[bf] = (double)S;
        g_pm[bf] = M2;
        __threadfence();                       // release partials
        unsigned old = atomicAdd(&g_cnt_t, 1u);
        s_fin = (old == NBLK - 1) ? 1 : 0;
    }
    __syncthreads();
    if (!s_fin) return;

    // ---- finisher: last tile block reduces partials + writes outputs ----
    __threadfence();                           // acquire all partials
    double s = 0.0; float mm = 0.0f;
    for (int i = tid; i < NBLK; i += 256) {
        s += g_ps[i];
        mm = fmaxf(mm, g_pm[i]);
    }
#pragma unroll
    for (int off = 32; off > 0; off >>= 1) {
        s += __shfl_down(s, off);
        mm = fmaxf(mm, __shfl_down(mm, off));
    }
    __shared__ double sd[4];
    __shared__ float sf[4];
    if (lane == 0) { sd[wid] = s; sf[wid] = mm; }
    __syncthreads();
    if (tid == 0) {
        double S = (sd[0] + sd[1]) + (sd[2] + sd[3]);
        float M = fmaxf(fmaxf(sf[0], sf[1]), fmaxf(sf[2], sf[3]));
        // wait for the selector's published median (normally long done)
        while (atomicAdd(&g_flag, 0u) == 0u) __builtin_amdgcn_s_sleep(2);
        __threadfence();                       // acquire g_med
        unsigned u = g_med;
        // reset handshake state for the next call (graph-safe lifecycle)
        atomicExch(&g_flag, 0u);
        atomicExch(&g_cnt_t, 0u);
        unsigned bits = (u & 0x80000000u) ? (u ^ 0x80000000u) : ~u;
        float med = __uint_as_float(bits);
        out[0] = (float)(S / (double)NVOX);
        out[1] = M;
        out[2] = med * med;
    }
}

extern "C" void kernel_launch(void* const* d_in, const int* in_sizes, int n_in,
                              void* d_out, int out_size, void* d_ws, size_t ws_size,
                              hipStream_t stream) {
    const float* P = (const float*)d_in[0];
    float* out = (float*)d_out;

    hipLaunchKernelGGL(fused_main, dim3(NGRID), dim3(256), 0, stream, P, out);
}

// Round 2
// 110.123 us; speedup vs baseline: 1.1665x; 1.1665x over previous
//
#include <hip/hip_runtime.h>

// Problem dims
#define NZ 128
#define NY 192
#define NXP 193
#define NX 192
#define NVOX (NZ * NY * NX)
#define NZ0 (NZ * NY)      // 24576

// Tile: 32 x 16 xy outputs per block, 8 z-outputs per thread.
// Two y-chains (y, y+8) packed into the two f16 lanes of a native _Float16x2
// (R10: WIN). R11: z-loop NOT unrolled (small I-footprint).
// R12 FAILED (95.8 -> 128.5): single-kernel fusion used __threadfence() in
// every block; on gfx950 device-scope fences lower to buffer_wbl2/buffer_inv
// (per-XCD L2 writeback/invalidate) -> ~1150 serialized L2 scans ~= +60 us.
// R13: same fusion, but ALL cross-block traffic is relaxed AGENT-SCOPE
// ATOMICS (sc1, executed at the MALL coherence point, no cache maintenance).
// Ordering data->counter via per-thread "s_waitcnt vmcnt(0)" + barrier, then
// a relaxed agent-scope RMW on the counter. Zero fences anywhere.
#define TX 32
#define TY 16
#define TZ 8
#define LX 34              // TX + 2
#define LYP 10             // packed rows r=0..9 (low: d rows -1..8, high: 7..16)
#define LZ 10              // TZ + 2
#define LSLP (LYP * LX)    // 340 packed entries per z-slice
#define LTOTP (LZ * LSLP)  // 3400 half2 = 13600 B

#define GX (NX / TX)       // 6
#define GY (NY / TY)       // 12
#define GZ (NZ / TZ)       // 16
#define NBLK (GX * GY * GZ) // 1152
#define ZB (NZ0 / 256)     // 96 z0-gather blocks (dispatched first)
#define NGRID (ZB + 1 + NBLK) // gathers + selector + tiles

// Device-global scratch. Lifecycle: every counter/flag returns to 0 before
// the dispatch ends (reset by its last consumer), g_hist re-zeroed by the
// selector, g_ps/g_pm/g_u/g_med fully overwritten every call before read.
// ALL cross-block accesses to these go through relaxed agent-scope atomics.
__device__ unsigned long long g_ps[NBLK];   // double bits
__device__ float    g_pm[NBLK];
__device__ unsigned g_hist[2048];
__device__ unsigned g_u[NZ0];
__device__ unsigned g_cnt_g;   // gather blocks done
__device__ unsigned g_cnt_t;   // tile blocks done
__device__ unsigned g_flag;    // median published
__device__ unsigned g_med;     // sortable-encoded median

#define ALD(p)    __hip_atomic_load((p), __ATOMIC_RELAXED, __HIP_MEMORY_SCOPE_AGENT)
#define AST(p, v) __hip_atomic_store((p), (v), __ATOMIC_RELAXED, __HIP_MEMORY_SCOPE_AGENT)
#define AADD(p,v) __hip_atomic_fetch_add((p), (v), __ATOMIC_RELAXED, __HIP_MEMORY_SCOPE_AGENT)
#define DRAIN()   asm volatile("s_waitcnt vmcnt(0)" ::: "memory")

__device__ __forceinline__ int refl(int i, int n) {
    i = (i < 0) ? -i : i;
    i = (i >= n) ? (2 * n - 2 - i) : i;
    return i;
}

__device__ __forceinline__ unsigned f2sortable(float f) {
    unsigned bits = __float_as_uint(f);
    return bits ^ ((bits & 0x80000000u) ? 0xFFFFFFFFu : 0x80000000u);
}

// Native packed f16 pair: clang ext vector, no hip_fp16.h API dependence.
typedef _Float16 H2 __attribute__((ext_vector_type(2)));

static __device__ __forceinline__ H2 h2min(H2 a, H2 b) { return __builtin_elementwise_min(a, b); }
static __device__ __forceinline__ H2 h2max(H2 a, H2 b) { return __builtin_elementwise_max(a, b); }

// ---- Batcher odd-even merge / sort on packed pairs (topology verified
// rounds 2-10; unused merge outputs are DCE'd by the compiler) ----
template<int M, int N>
struct OEM {
    static __device__ __forceinline__ void run(const H2* a, const H2* b, H2* out) {
        if constexpr (M == 0) {
#pragma unroll
            for (int i = 0; i < N; ++i) out[i] = b[i];
        } else if constexpr (N == 0) {
#pragma unroll
            for (int i = 0; i < M; ++i) out[i] = a[i];
        } else if constexpr (M == 1 && N == 1) {
            out[0] = h2min(a[0], b[0]);
            out[1] = h2max(a[0], b[0]);
        } else {
            constexpr int ME = (M + 1) / 2, MO = M / 2, NE = (N + 1) / 2, NO = N / 2;
            H2 ae[ME], be[NE];
            H2 ao[MO > 0 ? MO : 1], bo[NO > 0 ? NO : 1];
#pragma unroll
            for (int i = 0; i < ME; ++i) ae[i] = a[2 * i];
#pragma unroll
            for (int i = 0; i < MO; ++i) ao[i] = a[2 * i + 1];
#pragma unroll
            for (int i = 0; i < NE; ++i) be[i] = b[2 * i];
#pragma unroll
            for (int i = 0; i < NO; ++i) bo[i] = b[2 * i + 1];
            constexpr int EL = ME + NE, OL = MO + NO;
            H2 e[EL];
            H2 o[OL > 0 ? OL : 1];
            OEM<ME, NE>::run(ae, be, e);
            OEM<MO, NO>::run(ao, bo, o);
            constexpr int P = (OL < EL - 1) ? OL : (EL - 1);
            out[0] = e[0];
#pragma unroll
            for (int i = 0; i < P; ++i) {
                out[2 * i + 1] = h2min(o[i], e[i + 1]);
                out[2 * i + 2] = h2max(o[i], e[i + 1]);
            }
            if constexpr (EL == OL)           out[M + N - 1] = o[OL - 1];
            else if constexpr (EL == OL + 2)  out[M + N - 1] = e[EL - 1];
        }
    }
};

template<int N>
struct OES {
    static __device__ __forceinline__ void run(const H2* in, H2* out) {
        if constexpr (N == 1) {
            out[0] = in[0];
        } else {
            constexpr int H = N / 2;
            H2 s1[H], s2[N - H];
            OES<H>::run(in, s1);
            OES<N - H>::run(in + H, s2);
            OEM<H, N - H>::run(s1, s2, out);
        }
    }
};

// med27 = min( M[13], min_i max(A[i], M[12-i]) ), packed over both chains
__device__ __forceinline__ H2 sel27(const H2* A, const H2* M) {
    H2 t0 = h2max(A[0], M[12]);
    H2 t1 = h2max(A[1], M[11]);
    H2 t2 = h2max(A[2], M[10]);
    H2 t3 = h2max(A[3], M[9]);
    H2 t4 = h2max(A[4], M[8]);
    H2 t5 = h2max(A[5], M[7]);
    H2 t6 = h2max(A[6], M[6]);
    H2 t7 = h2max(A[7], M[5]);
    H2 t8 = h2max(A[8], M[4]);
    H2 r0 = h2min(h2min(t0, t1), h2min(t2, t3));
    H2 r1 = h2min(h2min(t4, t5), h2min(t6, t7));
    return h2min(h2min(r0, r1), h2min(t8, M[13]));
}

// Rank-locate across NB = PER*256 buckets with 256 threads (4 waves).
// v[] = this thread's PER bucket counts (caller loads them — global counts
// must come in via agent-scope atomic loads, LDS counts via plain reads).
// Writes *s_b = bucket index containing rank kk, *s_r = rank within bucket.
// Ends with __syncthreads() so callers may read s_b/s_r immediately.
template<int PER>
__device__ __forceinline__ void pick256v(const unsigned* v, unsigned kk,
                                         unsigned* s_b, unsigned* s_r,
                                         unsigned* wsum, unsigned* woff) {
    const int tid = threadIdx.x;
    const int lane = tid & 63, wid = tid >> 6;
    unsigned mysum = 0u;
#pragma unroll
    for (int j = 0; j < PER; ++j) mysum += v[j];
    unsigned inc = mysum;
#pragma unroll
    for (int d = 1; d < 64; d <<= 1) { unsigned t = __shfl_up(inc, d); if (lane >= d) inc += t; }
    if (lane == 63) wsum[wid] = inc;
    __syncthreads();
    if (tid == 0) { unsigned a = 0; for (int w = 0; w < 4; ++w) { woff[w] = a; a += wsum[w]; } }
    __syncthreads();
    unsigned exc = woff[wid] + inc - mysum;
#pragma unroll
    for (int j = 0; j < PER; ++j) {
        if (exc <= kk && kk < exc + v[j]) { *s_b = (unsigned)(tid * PER + j); *s_r = kk - exc; }
        exc += v[j];
    }
    __syncthreads();
}

// Fused single kernel:
//   blocks 0..ZB-1      : z0 gather + global histogram, signal g_cnt_g
//   block  ZB           : selector — waits for gathers, computes the global
//                         median (overlapped with tile compute), publishes it
//   blocks ZB+1..ZB+NBLK: loss tiles; the LAST one to finish reduces the
//                         per-block partials and writes out[0..2]
__global__ __launch_bounds__(256, 4) void fused_main(const float* __restrict__ P,
                                                     float* __restrict__ out) {
    __shared__ H2 dt[LTOTP];
    const int tid = threadIdx.x;
    const int bid = blockIdx.x;

    if (bid < ZB) {
        // ---- z0 gather + histogram role (exact f32 path, untouched) ----
        unsigned* h = (unsigned*)dt;
        for (int j = tid; j < 2048; j += 256) h[j] = 0u;
        __syncthreads();
        const int i = bid * 256 + tid;
        unsigned u = f2sortable(P[(size_t)i * NXP]);
        AST(&g_u[i], u);                    // sc1 store, coherent at MALL
        atomicAdd(&h[u >> 21], 1u);
        __syncthreads();
        for (int j = tid; j < 2048; j += 256) {
            unsigned c = h[j];
            if (c) atomicAdd(&g_hist[j], c);   // device-scope atomic (MALL)
        }
        // every thread drains its own sc1 stores/atomics, barrier, then signal
        DRAIN();
        __syncthreads();
        if (tid == 0) AADD(&g_cnt_g, 1u);
        return;
    }

    if (bid == ZB) {
        // ---- selector role: median select overlapped with tile compute ----
        __shared__ unsigned wsum[4], woff[4];
        __shared__ unsigned s_b, s_r, s_cnt, s_med;
        unsigned* cand = (unsigned*)dt;   // reuse tile LDS (13600 B >= 8192)
        const unsigned kk = (NZ0 - 1) / 2;   // 12287

        if (tid == 0) {
            while (ALD(&g_cnt_g) < ZB) __builtin_amdgcn_s_sleep(2);
        }
        __syncthreads();

        // 1. pick the top-11-bit bucket containing rank kk (sc1 loads)
        {
            unsigned v[8];
#pragma unroll
            for (int j = 0; j < 8; ++j) v[j] = ALD(&g_hist[tid * 8 + j]);
            pick256v<8>(v, kk, &s_b, &s_r, wsum, woff);
        }
        const unsigned b1 = s_b, k1 = s_r;
        // re-zero g_hist for the next call (sc1 stores so next call's MALL
        // atomics see the zeros; ordered by the kernel-end release)
        for (int j = tid; j < 2048; j += 256) AST(&g_hist[j], 0u);

        // 2. gather in-bucket candidates, exact counting-select
        if (tid == 0) s_cnt = 0u;
        __syncthreads();
        for (int i = tid; i < NZ0; i += 256) {
            unsigned u = ALD(&g_u[i]);
            if ((u >> 21) == b1) {
                unsigned idx = atomicAdd(&s_cnt, 1u);
                if (idx < 2048u) cand[idx] = u;
            }
        }
        __syncthreads();
        const unsigned m = s_cnt;

        if (m <= 2048u) {
            for (int i = tid; i < (int)m; i += 256) {
                unsigned c = cand[i], less = 0u, eq = 0u;
                for (unsigned j = 0; j < m; ++j) {
                    unsigned v = cand[j];
                    less += (v < c); eq += (v == c);
                }
                if (less <= k1 && k1 < less + eq) s_med = c;
            }
            __syncthreads();
        } else {
            // fallback: 11-bit + 10-bit radix passes over g_u (filtered)
            unsigned pref = b1, kx = k1;
            for (int j = tid; j < 2048; j += 256) cand[j] = 0u;
            __syncthreads();
            for (int i = tid; i < NZ0; i += 256) {
                unsigned u = ALD(&g_u[i]);
                if ((u >> 21) == pref) atomicAdd(&cand[(u >> 10) & 2047u], 1u);
            }
            __syncthreads();
            {
                unsigned v[8];
#pragma unroll
                for (int j = 0; j < 8; ++j) v[j] = cand[tid * 8 + j];
                pick256v<8>(v, kx, &s_b, &s_r, wsum, woff);
            }
            pref = (pref << 11) | s_b; kx = s_r;
            __syncthreads();
            for (int j = tid; j < 1024; j += 256) cand[j] = 0u;
            __syncthreads();
            for (int i = tid; i < NZ0; i += 256) {
                unsigned u = ALD(&g_u[i]);
                if ((u >> 10) == pref) atomicAdd(&cand[u & 1023u], 1u);
            }
            __syncthreads();
            {
                unsigned v[4];
#pragma unroll
                for (int j = 0; j < 4; ++j) v[j] = cand[tid * 4 + j];
                pick256v<4>(v, kx, &s_b, &s_r, wsum, woff);
            }
            if (tid == 0) s_med = (pref << 10) | s_b;
            __syncthreads();
        }

        // publish median; reset gather counter for the next call
        if (tid == 0) {
            AST(&g_med, s_med);
            AST(&g_cnt_g, 0u);
            DRAIN();                     // g_med/g_cnt_g complete before flag
            AST(&g_flag, 1u);
        }
        return;
    }

    // ---- loss tile role ----
    const int bf = bid - ZB - 1;
    const int bx = bf % GX;
    const int brem = bf / GX;
    const int by = brem % GY;
    const int bz = brem / GY;
    const int x0 = bx * TX, y0 = by * TY, z0t = bz * TZ;

    // Stage packed d-tile into LDS. Entry p: xx = p%LX, rr = p/LX; low half
    // from d row y0+rr-1, high half from d row y0+rr+7 (both reflect-mapped).
    int offL[2], offH[2], lp[2];
#pragma unroll
    for (int k = 0; k < 2; ++k) {
        int p = tid + 256 * k;
        lp[k] = (p < LSLP) ? p : -1;
        if (p < LSLP) {
            int xx = p % LX, rr = p / LX;
            int gx  = refl(x0 + xx - 1, NX);
            int gyL = refl(y0 + rr - 1, NY);
            int gyH = refl(y0 + rr + 7, NY);
            offL[k] = gyL * NXP + gx;
            offH[k] = gyH * NXP + gx;
        }
    }
    for (int zz = 0; zz < LZ; ++zz) {
        int gz = refl(z0t + zz - 1, NZ);
        const float* __restrict__ pl = P + (size_t)gz * (NY * NXP);
#pragma unroll
        for (int k = 0; k < 2; ++k) {
            if (lp[k] >= 0) {
                float dL = pl[offL[k] + 1] - pl[offL[k]];
                float dH = pl[offH[k] + 1] - pl[offH[k]];
                H2 v;
                v.x = (_Float16)dL;
                v.y = (_Float16)dH;
                dt[zz * LSLP + lp[k]] = v;
            }
        }
    }
    __syncthreads();

    const int x = tid & 31;
    const int y = tid >> 5;            // 0..7; packed rows y..y+2 serve y and y+8
    const int rbase = y * LX + x;

    auto rd9 = [&](int base, H2* v) {
#pragma unroll
        for (int dy = 0; dy < 3; ++dy)
#pragma unroll
            for (int dxx = 0; dxx < 3; ++dxx)
                v[dy * 3 + dxx] = dt[base + dy * LX + dxx];
    };

    H2 S0[9], S1[9], S2[9], T[9], M[18];
    H2 c2, m2 = (H2)((_Float16)0.0f);
    const H2 one2 = (H2)((_Float16)1.0f);
    float s_acc = 0.0f;

    // Warm-up: sorted slices 0 (S0) and 1 (S1); center of slice 1.
    rd9(rbase, T);            OES<9>::run(T, S0);
    rd9(rbase + LSLP, T);     c2 = T[4];
    OES<9>::run(T, S1);

    auto accum = [&](H2 med) {
        H2 df = c2 - med;
        float dl = (float)df.x, dh = (float)df.y;
        s_acc = fmaf(dl, dl, fmaf(dh, dh, s_acc));
        m2 = h2max(m2, one2 - c2);
    };

    // Invariant at pair t: S0 = sorted slice t (oldest), S1 = sorted t+1.
    // NOT unrolled: single ~2KB body keeps the I-footprint small (R11).
    int sl = rbase + 2 * LSLP;
#pragma unroll 1
    for (int t = 0; t < TZ; t += 2) {
        rd9(sl, T);
        H2 cn = T[4];
        OES<9>::run(T, S2);
        OEM<9, 9>::run(S1, S2, M);
        accum(sel27(S0, M));
        c2 = cn;
        sl += LSLP;

        rd9(sl, T);
        cn = T[4];
        OES<9>::run(T, S0);
        accum(sel27(S0, M));
        c2 = cn;
        sl += LSLP;

        // Rotate for next pair: S0' = sorted(t+2) = S2, S1' = sorted(t+3) = S0.
#pragma unroll
        for (int i = 0; i < 9; ++i) {
            H2 tmp = S0[i];
            S0[i] = S2[i];
            S1[i] = tmp;
        }
    }

    float m_acc = fmaxf((float)m2.x, (float)m2.y);

    // Block reduction -> per-block partial.
#pragma unroll
    for (int off = 32; off > 0; off >>= 1) {
        s_acc += __shfl_down(s_acc, off);
        m_acc = fmaxf(m_acc, __shfl_down(m_acc, off));
    }
    __shared__ float ss[4], sm[4];
    __shared__ int s_fin;
    const int lane = tid & 63, wid = tid >> 6;
    if (lane == 0) { ss[wid] = s_acc; sm[wid] = m_acc; }
    __syncthreads();
    if (tid == 0) {
        float S = (ss[0] + ss[1]) + (ss[2] + ss[3]);
        float M2 = fmaxf(fmaxf(sm[0], sm[1]), fmaxf(sm[2], sm[3]));
        AST(&g_ps[bf], (unsigned long long)__double_as_longlong((double)S));
        AST(&g_pm[bf], M2);
        DRAIN();                               // partials complete before count
        unsigned old = AADD(&g_cnt_t, 1u);
        s_fin = (old == NBLK - 1) ? 1 : 0;
    }
    __syncthreads();
    if (!s_fin) return;

    // ---- finisher: last tile block reduces partials + writes outputs ----
    double s = 0.0; float mm = 0.0f;
    for (int i = tid; i < NBLK; i += 256) {
        s += __longlong_as_double((long long)ALD(&g_ps[i]));
        mm = fmaxf(mm, ALD(&g_pm[i]));
    }
#pragma unroll
    for (int off = 32; off > 0; off >>= 1) {
        s += __shfl_down(s, off);
        mm = fmaxf(mm, __shfl_down(mm, off));
    }
    __shared__ double sd[4];
    __shared__ float sf[4];
    if (lane == 0) { sd[wid] = s; sf[wid] = mm; }
    __syncthreads();
    if (tid == 0) {
        double S = (sd[0] + sd[1]) + (sd[2] + sd[3]);
        float M = fmaxf(fmaxf(sf[0], sf[1]), fmaxf(sf[2], sf[3]));
        // wait for the selector's published median (normally long done)
        while (ALD(&g_flag) == 0u) __builtin_amdgcn_s_sleep(2);
        unsigned u = ALD(&g_med);
        // reset handshake state for the next call (graph-safe lifecycle)
        AST(&g_flag, 0u);
        AST(&g_cnt_t, 0u);
        unsigned bits = (u & 0x80000000u) ? (u ^ 0x80000000u) : ~u;
        float med = __uint_as_float(bits);
        out[0] = (float)(S / (double)NVOX);
        out[1] = M;
        out[2] = med * med;
    }
}

extern "C" void kernel_launch(void* const* d_in, const int* in_sizes, int n_in,
                              void* d_out, int out_size, void* d_ws, size_t ws_size,
                              hipStream_t stream) {
    const float* P = (const float*)d_in[0];
    float* out = (float*)d_out;

    hipLaunchKernelGGL(fused_main, dim3(NGRID), dim3(256), 0, stream, P, out);
}

// Round 3
// 90.316 us; speedup vs baseline: 1.4223x; 1.2193x over previous
//
#include <hip/hip_runtime.h>

// Problem dims
#define NZ 128
#define NY 192
#define NXP 193
#define NX 192
#define NVOX (NZ * NY * NX)
#define NZ0 (NZ * NY)      // 24576

// Tile: 32 x 16 xy outputs per block, 8 z-outputs per thread; two y-chains
// packed into _Float16x2 lanes (R10 WIN). z-loop not unrolled (R11).
// R12 FAILED (128.5): __threadfence() in every block -> buffer_wbl2/inv storm.
// R13 FAILED (110.1): fences gone, but consumer-side AGENT-SCOPE ATOMIC LOADS
// (sc0/sc1 = L1+L2 bypass) serialize: the selector's NZ0 scan = 96 MALL
// round-trips/thread ~= 32 us; zero-HBM replay still took 48.9 us => latency.
// R14: producers unchanged (sc1 stores / device atomics -> MALL, proven
// correct in R13). Consumers of single-reader read-after-all-writes arrays
// (g_u, g_hist, g_ps, g_pm) use PLAIN VECTORIZED loads: caches invalidated at
// dispatch start + no prior touch on the reader's XCD => first touch misses
// => fresh from MALL, fully pipelined. POLLED flags stay atomic (a cached
// poll would spin on a stale line forever).
#define TX 32
#define TY 16
#define TZ 8
#define LX 34              // TX + 2
#define LYP 10             // packed rows r=0..9 (low: d rows -1..8, high: 7..16)
#define LZ 10              // TZ + 2
#define LSLP (LYP * LX)    // 340 packed entries per z-slice
#define LTOTP (LZ * LSLP)  // 3400 half2 = 13600 B

#define GX (NX / TX)       // 6
#define GY (NY / TY)       // 12
#define GZ (NZ / TZ)       // 16
#define NBLK (GX * GY * GZ) // 1152
#define ZB (NZ0 / 256)     // 96 z0-gather blocks (dispatched first)
#define NGRID (ZB + 1 + NBLK) // gathers + selector + tiles

// Device-global scratch. Lifecycle: counters/flags return to 0 before the
// dispatch ends (reset by last consumer); g_hist re-zeroed by the selector;
// g_ps/g_pm/g_u/g_med fully overwritten every call before being read.
__device__ __align__(16) unsigned long long g_ps[NBLK];   // double bits
__device__ __align__(16) float    g_pm[NBLK];
__device__ __align__(16) unsigned g_hist[2048];
__device__ __align__(16) unsigned g_u[NZ0];
__device__ unsigned g_cnt_g;   // gather blocks done
__device__ unsigned g_cnt_t;   // tile blocks done
__device__ unsigned g_flag;    // median published
__device__ unsigned g_med;     // sortable-encoded median

#define ALD(p)    __hip_atomic_load((p), __ATOMIC_RELAXED, __HIP_MEMORY_SCOPE_AGENT)
#define AST(p, v) __hip_atomic_store((p), (v), __ATOMIC_RELAXED, __HIP_MEMORY_SCOPE_AGENT)
#define AADD(p,v) __hip_atomic_fetch_add((p), (v), __ATOMIC_RELAXED, __HIP_MEMORY_SCOPE_AGENT)
#define DRAIN()   asm volatile("s_waitcnt vmcnt(0)" ::: "memory")

__device__ __forceinline__ int refl(int i, int n) {
    i = (i < 0) ? -i : i;
    i = (i >= n) ? (2 * n - 2 - i) : i;
    return i;
}

__device__ __forceinline__ unsigned f2sortable(float f) {
    unsigned bits = __float_as_uint(f);
    return bits ^ ((bits & 0x80000000u) ? 0xFFFFFFFFu : 0x80000000u);
}

// Native packed f16 pair: clang ext vector, no hip_fp16.h API dependence.
typedef _Float16 H2 __attribute__((ext_vector_type(2)));

static __device__ __forceinline__ H2 h2min(H2 a, H2 b) { return __builtin_elementwise_min(a, b); }
static __device__ __forceinline__ H2 h2max(H2 a, H2 b) { return __builtin_elementwise_max(a, b); }

// ---- Batcher odd-even merge / sort on packed pairs (topology verified
// rounds 2-10; unused merge outputs are DCE'd by the compiler) ----
template<int M, int N>
struct OEM {
    static __device__ __forceinline__ void run(const H2* a, const H2* b, H2* out) {
        if constexpr (M == 0) {
#pragma unroll
            for (int i = 0; i < N; ++i) out[i] = b[i];
        } else if constexpr (N == 0) {
#pragma unroll
            for (int i = 0; i < M; ++i) out[i] = a[i];
        } else if constexpr (M == 1 && N == 1) {
            out[0] = h2min(a[0], b[0]);
            out[1] = h2max(a[0], b[0]);
        } else {
            constexpr int ME = (M + 1) / 2, MO = M / 2, NE = (N + 1) / 2, NO = N / 2;
            H2 ae[ME], be[NE];
            H2 ao[MO > 0 ? MO : 1], bo[NO > 0 ? NO : 1];
#pragma unroll
            for (int i = 0; i < ME; ++i) ae[i] = a[2 * i];
#pragma unroll
            for (int i = 0; i < MO; ++i) ao[i] = a[2 * i + 1];
#pragma unroll
            for (int i = 0; i < NE; ++i) be[i] = b[2 * i];
#pragma unroll
            for (int i = 0; i < NO; ++i) bo[i] = b[2 * i + 1];
            constexpr int EL = ME + NE, OL = MO + NO;
            H2 e[EL];
            H2 o[OL > 0 ? OL : 1];
            OEM<ME, NE>::run(ae, be, e);
            OEM<MO, NO>::run(ao, bo, o);
            constexpr int P = (OL < EL - 1) ? OL : (EL - 1);
            out[0] = e[0];
#pragma unroll
            for (int i = 0; i < P; ++i) {
                out[2 * i + 1] = h2min(o[i], e[i + 1]);
                out[2 * i + 2] = h2max(o[i], e[i + 1]);
            }
            if constexpr (EL == OL)           out[M + N - 1] = o[OL - 1];
            else if constexpr (EL == OL + 2)  out[M + N - 1] = e[EL - 1];
        }
    }
};

template<int N>
struct OES {
    static __device__ __forceinline__ void run(const H2* in, H2* out) {
        if constexpr (N == 1) {
            out[0] = in[0];
        } else {
            constexpr int H = N / 2;
            H2 s1[H], s2[N - H];
            OES<H>::run(in, s1);
            OES<N - H>::run(in + H, s2);
            OEM<H, N - H>::run(s1, s2, out);
        }
    }
};

// med27 = min( M[13], min_i max(A[i], M[12-i]) ), packed over both chains
__device__ __forceinline__ H2 sel27(const H2* A, const H2* M) {
    H2 t0 = h2max(A[0], M[12]);
    H2 t1 = h2max(A[1], M[11]);
    H2 t2 = h2max(A[2], M[10]);
    H2 t3 = h2max(A[3], M[9]);
    H2 t4 = h2max(A[4], M[8]);
    H2 t5 = h2max(A[5], M[7]);
    H2 t6 = h2max(A[6], M[6]);
    H2 t7 = h2max(A[7], M[5]);
    H2 t8 = h2max(A[8], M[4]);
    H2 r0 = h2min(h2min(t0, t1), h2min(t2, t3));
    H2 r1 = h2min(h2min(t4, t5), h2min(t6, t7));
    return h2min(h2min(r0, r1), h2min(t8, M[13]));
}

// Rank-locate across NB = PER*256 buckets with 256 threads (4 waves).
// v[] = this thread's PER bucket counts. Writes *s_b = bucket containing
// rank kk, *s_r = rank within bucket. Ends with __syncthreads().
template<int PER>
__device__ __forceinline__ void pick256v(const unsigned* v, unsigned kk,
                                         unsigned* s_b, unsigned* s_r,
                                         unsigned* wsum, unsigned* woff) {
    const int tid = threadIdx.x;
    const int lane = tid & 63, wid = tid >> 6;
    unsigned mysum = 0u;
#pragma unroll
    for (int j = 0; j < PER; ++j) mysum += v[j];
    unsigned inc = mysum;
#pragma unroll
    for (int d = 1; d < 64; d <<= 1) { unsigned t = __shfl_up(inc, d); if (lane >= d) inc += t; }
    if (lane == 63) wsum[wid] = inc;
    __syncthreads();
    if (tid == 0) { unsigned a = 0; for (int w = 0; w < 4; ++w) { woff[w] = a; a += wsum[w]; } }
    __syncthreads();
    unsigned exc = woff[wid] + inc - mysum;
#pragma unroll
    for (int j = 0; j < PER; ++j) {
        if (exc <= kk && kk < exc + v[j]) { *s_b = (unsigned)(tid * PER + j); *s_r = kk - exc; }
        exc += v[j];
    }
    __syncthreads();
}

// Fused single kernel:
//   blocks 0..ZB-1      : z0 gather + global histogram, signal g_cnt_g
//   block  ZB           : selector — waits for gathers, computes the global
//                         median (overlapped with tile compute), publishes it
//   blocks ZB+1..ZB+NBLK: loss tiles; the LAST one to finish reduces the
//                         per-block partials and writes out[0..2]
__global__ __launch_bounds__(256, 4) void fused_main(const float* __restrict__ P,
                                                     float* __restrict__ out) {
    __shared__ H2 dt[LTOTP];
    const int tid = threadIdx.x;
    const int bid = blockIdx.x;

    if (bid < ZB) {
        // ---- z0 gather + histogram role (exact f32 path, untouched) ----
        unsigned* h = (unsigned*)dt;
        for (int j = tid; j < 2048; j += 256) h[j] = 0u;
        __syncthreads();
        const int i = bid * 256 + tid;
        unsigned u = f2sortable(P[(size_t)i * NXP]);
        AST(&g_u[i], u);                    // sc1 store -> MALL (proven R13)
        atomicAdd(&h[u >> 21], 1u);
        __syncthreads();
        for (int j = tid; j < 2048; j += 256) {
            unsigned c = h[j];
            if (c) atomicAdd(&g_hist[j], c);   // device-scope atomic (MALL)
        }
        // every thread drains its own sc1 stores/atomics, barrier, then signal
        DRAIN();
        __syncthreads();
        if (tid == 0) AADD(&g_cnt_g, 1u);
        return;
    }

    if (bid == ZB) {
        // ---- selector role: median select overlapped with tile compute ----
        __shared__ unsigned wsum[4], woff[4];
        __shared__ unsigned s_b, s_r, s_cnt, s_med;
        unsigned* cand = (unsigned*)dt;   // reuse tile LDS (13600 B >= 8192)
        const unsigned kk = (NZ0 - 1) / 2;   // 12287

        if (tid == 0) {
            while (ALD(&g_cnt_g) < ZB) __builtin_amdgcn_s_sleep(2);   // polled: atomic
        }
        __syncthreads();   // also a compiler barrier: plain loads below stay below

        // 1. pick the top-11-bit bucket containing rank kk.
        // PLAIN vectorized loads: single reader, first touch after all MALL
        // atomics, dispatch-start invalidate => guaranteed fresh miss.
        {
            const uint4* __restrict__ gh4 = reinterpret_cast<const uint4*>(g_hist);
            uint4 a = gh4[tid * 2], b = gh4[tid * 2 + 1];
            unsigned v[8] = {a.x, a.y, a.z, a.w, b.x, b.y, b.z, b.w};
            pick256v<8>(v, kk, &s_b, &s_r, wsum, woff);
        }
        const unsigned b1 = s_b, k1 = s_r;
        // re-zero g_hist for the next call (sc1 stores -> MALL)
        for (int j = tid; j < 2048; j += 256) AST(&g_hist[j], 0u);

        // 2. gather in-bucket candidates (plain uint4 loads), counting-select
        if (tid == 0) s_cnt = 0u;
        __syncthreads();
        {
            const uint4* __restrict__ gu4 = reinterpret_cast<const uint4*>(g_u);
            for (int i = tid; i < NZ0 / 4; i += 256) {
                uint4 q = gu4[i];
                unsigned w[4] = {q.x, q.y, q.z, q.w};
#pragma unroll
                for (int j = 0; j < 4; ++j) {
                    if ((w[j] >> 21) == b1) {
                        unsigned idx = atomicAdd(&s_cnt, 1u);
                        if (idx < 2048u) cand[idx] = w[j];
                    }
                }
            }
        }
        __syncthreads();
        const unsigned m = s_cnt;

        if (m <= 2048u) {
            for (int i = tid; i < (int)m; i += 256) {
                unsigned c = cand[i], less = 0u, eq = 0u;
                for (unsigned j = 0; j < m; ++j) {
                    unsigned v = cand[j];
                    less += (v < c); eq += (v == c);
                }
                if (less <= k1 && k1 < less + eq) s_med = c;
            }
            __syncthreads();
        } else {
            // fallback: 11-bit + 10-bit radix passes over g_u (filtered)
            unsigned pref = b1, kx = k1;
            for (int j = tid; j < 2048; j += 256) cand[j] = 0u;
            __syncthreads();
            {
                const uint4* __restrict__ gu4 = reinterpret_cast<const uint4*>(g_u);
                for (int i = tid; i < NZ0 / 4; i += 256) {
                    uint4 q = gu4[i];
                    unsigned w[4] = {q.x, q.y, q.z, q.w};
#pragma unroll
                    for (int j = 0; j < 4; ++j)
                        if ((w[j] >> 21) == pref) atomicAdd(&cand[(w[j] >> 10) & 2047u], 1u);
                }
            }
            __syncthreads();
            {
                unsigned v[8];
#pragma unroll
                for (int j = 0; j < 8; ++j) v[j] = cand[tid * 8 + j];
                pick256v<8>(v, kx, &s_b, &s_r, wsum, woff);
            }
            pref = (pref << 11) | s_b; kx = s_r;
            __syncthreads();
            for (int j = tid; j < 1024; j += 256) cand[j] = 0u;
            __syncthreads();
            {
                const uint4* __restrict__ gu4 = reinterpret_cast<const uint4*>(g_u);
                for (int i = tid; i < NZ0 / 4; i += 256) {
                    uint4 q = gu4[i];
                    unsigned w[4] = {q.x, q.y, q.z, q.w};
#pragma unroll
                    for (int j = 0; j < 4; ++j)
                        if ((w[j] >> 10) == pref) atomicAdd(&cand[w[j] & 1023u], 1u);
                }
            }
            __syncthreads();
            {
                unsigned v[4];
#pragma unroll
                for (int j = 0; j < 4; ++j) v[j] = cand[tid * 4 + j];
                pick256v<4>(v, kx, &s_b, &s_r, wsum, woff);
            }
            if (tid == 0) s_med = (pref << 10) | s_b;
            __syncthreads();
        }

        // publish median; reset gather counter for the next call
        if (tid == 0) {
            AST(&g_med, s_med);
            AST(&g_cnt_g, 0u);
            DRAIN();                     // g_med/g_cnt_g complete before flag
            AST(&g_flag, 1u);
        }
        return;
    }

    // ---- loss tile role ----
    const int bf = bid - ZB - 1;
    const int bx = bf % GX;
    const int brem = bf / GX;
    const int by = brem % GY;
    const int bz = brem / GY;
    const int x0 = bx * TX, y0 = by * TY, z0t = bz * TZ;

    // Stage packed d-tile into LDS. Entry p: xx = p%LX, rr = p/LX; low half
    // from d row y0+rr-1, high half from d row y0+rr+7 (both reflect-mapped).
    int offL[2], offH[2], lp[2];
#pragma unroll
    for (int k = 0; k < 2; ++k) {
        int p = tid + 256 * k;
        lp[k] = (p < LSLP) ? p : -1;
        if (p < LSLP) {
            int xx = p % LX, rr = p / LX;
            int gx  = refl(x0 + xx - 1, NX);
            int gyL = refl(y0 + rr - 1, NY);
            int gyH = refl(y0 + rr + 7, NY);
            offL[k] = gyL * NXP + gx;
            offH[k] = gyH * NXP + gx;
        }
    }
    for (int zz = 0; zz < LZ; ++zz) {
        int gz = refl(z0t + zz - 1, NZ);
        const float* __restrict__ pl = P + (size_t)gz * (NY * NXP);
#pragma unroll
        for (int k = 0; k < 2; ++k) {
            if (lp[k] >= 0) {
                float dL = pl[offL[k] + 1] - pl[offL[k]];
                float dH = pl[offH[k] + 1] - pl[offH[k]];
                H2 v;
                v.x = (_Float16)dL;
                v.y = (_Float16)dH;
                dt[zz * LSLP + lp[k]] = v;
            }
        }
    }
    __syncthreads();

    const int x = tid & 31;
    const int y = tid >> 5;            // 0..7; packed rows y..y+2 serve y and y+8
    const int rbase = y * LX + x;

    auto rd9 = [&](int base, H2* v) {
#pragma unroll
        for (int dy = 0; dy < 3; ++dy)
#pragma unroll
            for (int dxx = 0; dxx < 3; ++dxx)
                v[dy * 3 + dxx] = dt[base + dy * LX + dxx];
    };

    H2 S0[9], S1[9], S2[9], T[9], M[18];
    H2 c2, m2 = (H2)((_Float16)0.0f);
    const H2 one2 = (H2)((_Float16)1.0f);
    float s_acc = 0.0f;

    // Warm-up: sorted slices 0 (S0) and 1 (S1); center of slice 1.
    rd9(rbase, T);            OES<9>::run(T, S0);
    rd9(rbase + LSLP, T);     c2 = T[4];
    OES<9>::run(T, S1);

    auto accum = [&](H2 med) {
        H2 df = c2 - med;
        float dl = (float)df.x, dh = (float)df.y;
        s_acc = fmaf(dl, dl, fmaf(dh, dh, s_acc));
        m2 = h2max(m2, one2 - c2);
    };

    // Invariant at pair t: S0 = sorted slice t (oldest), S1 = sorted t+1.
    // NOT unrolled: single ~2KB body keeps the I-footprint small (R11).
    int sl = rbase + 2 * LSLP;
#pragma unroll 1
    for (int t = 0; t < TZ; t += 2) {
        rd9(sl, T);
        H2 cn = T[4];
        OES<9>::run(T, S2);
        OEM<9, 9>::run(S1, S2, M);
        accum(sel27(S0, M));
        c2 = cn;
        sl += LSLP;

        rd9(sl, T);
        cn = T[4];
        OES<9>::run(T, S0);
        accum(sel27(S0, M));
        c2 = cn;
        sl += LSLP;

        // Rotate for next pair: S0' = sorted(t+2) = S2, S1' = sorted(t+3) = S0.
#pragma unroll
        for (int i = 0; i < 9; ++i) {
            H2 tmp = S0[i];
            S0[i] = S2[i];
            S1[i] = tmp;
        }
    }

    float m_acc = fmaxf((float)m2.x, (float)m2.y);

    // Block reduction -> per-block partial.
#pragma unroll
    for (int off = 32; off > 0; off >>= 1) {
        s_acc += __shfl_down(s_acc, off);
        m_acc = fmaxf(m_acc, __shfl_down(m_acc, off));
    }
    __shared__ float ss[4], sm[4];
    __shared__ int s_fin;
    const int lane = tid & 63, wid = tid >> 6;
    if (lane == 0) { ss[wid] = s_acc; sm[wid] = m_acc; }
    __syncthreads();
    if (tid == 0) {
        float S = (ss[0] + ss[1]) + (ss[2] + ss[3]);
        float M2 = fmaxf(fmaxf(sm[0], sm[1]), fmaxf(sm[2], sm[3]));
        AST(&g_ps[bf], (unsigned long long)__double_as_longlong((double)S));
        AST(&g_pm[bf], M2);
        DRAIN();                               // partials complete before count
        unsigned old = AADD(&g_cnt_t, 1u);
        s_fin = (old == NBLK - 1) ? 1 : 0;
    }
    __syncthreads();   // orders the plain partial reads below after the RMW
    if (!s_fin) return;

    // ---- finisher: last tile block reduces partials + writes outputs ----
    // Plain loads: single reader, producers stored via sc1 (no L2 copies),
    // first touch on this XCD => fresh miss from MALL.
    double s = 0.0; float mm = 0.0f;
    for (int i = tid; i < NBLK; i += 256) {
        s += __longlong_as_double((long long)g_ps[i]);
        mm = fmaxf(mm, g_pm[i]);
    }
#pragma unroll
    for (int off = 32; off > 0; off >>= 1) {
        s += __shfl_down(s, off);
        mm = fmaxf(mm, __shfl_down(mm, off));
    }
    __shared__ double sd[4];
    __shared__ float sf[4];
    if (lane == 0) { sd[wid] = s; sf[wid] = mm; }
    __syncthreads();
    if (tid == 0) {
        double S = (sd[0] + sd[1]) + (sd[2] + sd[3]);
        float M = fmaxf(fmaxf(sf[0], sf[1]), fmaxf(sf[2], sf[3]));
        // wait for the selector's published median (polled: atomic)
        while (ALD(&g_flag) == 0u) __builtin_amdgcn_s_sleep(2);
        unsigned u = ALD(&g_med);
        // reset handshake state for the next call (graph-safe lifecycle)
        AST(&g_flag, 0u);
        AST(&g_cnt_t, 0u);
        unsigned bits = (u & 0x80000000u) ? (u ^ 0x80000000u) : ~u;
        float med = __uint_as_float(bits);
        out[0] = (float)(S / (double)NVOX);
        out[1] = M;
        out[2] = med * med;
    }
}

extern "C" void kernel_launch(void* const* d_in, const int* in_sizes, int n_in,
                              void* d_out, int out_size, void* d_ws, size_t ws_size,
                              hipStream_t stream) {
    const float* P = (const float*)d_in[0];
    float* out = (float*)d_out;

    hipLaunchKernelGGL(fused_main, dim3(NGRID), dim3(256), 0, stream, P, out);
}